// Round 1
// baseline (959.739 us; speedup 1.0000x reference)
//
#include <hip/hip_runtime.h>

// out = clip(hq - L(hq - lq), -1, 1)
// L = B16 . B8 . B4 . B2 . B1, Br = dilated 3x3 [1,2,1]x[1,2,1]/16, replicate pad.
// 48 independent planes of 720x1280 fp32.

static constexpr int IMG_H = 720;
static constexpr int IMG_W = 1280;
static constexpr int NPL   = 48;   // C(3) * f(16)

__device__ __forceinline__ float4 ld4(const float* p) {
    return *reinterpret_cast<const float4*>(p);
}
__device__ __forceinline__ void st4(float* p, const float4& v) {
    *reinterpret_cast<float4*>(p) = v;
}

template<bool DIFF>
__device__ __forceinline__ float4 load4(const float* a, const float* b, int off) {
    float4 v = ld4(a + off);
    if constexpr (DIFF) {
        float4 u = ld4(b + off);
        v.x -= u.x; v.y -= u.y; v.z -= u.z; v.w -= u.w;
    }
    return v;
}
template<bool DIFF>
__device__ __forceinline__ float load1(const float* a, const float* b, int off) {
    float v = a[off];
    if constexpr (DIFF) v -= b[off];
    return v;
}

// Horizontal 3-tap dilated blur producing 4 consecutive outputs at x0..x0+3.
// a (and b if DIFF) point at the start of the row.
template<int R, bool DIFF>
__device__ __forceinline__ float4 hblur(const float* a, const float* b, int x0) {
    float4 h;
    constexpr int LO = (R >= 4) ? R : 4;
    if (x0 >= LO && x0 + LO + 4 <= IMG_W) {
        // fast path: all taps in-bounds, aligned float4 loads
        float4 L, C, Rt;
        C = load4<DIFF>(a, b, x0);
        if constexpr (R >= 4) {
            L  = load4<DIFF>(a, b, x0 - R);
            Rt = load4<DIFF>(a, b, x0 + R);
        } else {
            float4 A = load4<DIFF>(a, b, x0 - 4);
            float4 B = load4<DIFF>(a, b, x0 + 4);
            if constexpr (R == 1) {
                L  = make_float4(A.w, C.x, C.y, C.z);
                Rt = make_float4(C.y, C.z, C.w, B.x);
            } else { // R == 2
                L  = make_float4(A.z, A.w, C.x, C.y);
                Rt = make_float4(C.z, C.w, B.x, B.y);
            }
        }
        h.x = 0.25f * (L.x + 2.f * C.x + Rt.x);
        h.y = 0.25f * (L.y + 2.f * C.y + Rt.y);
        h.z = 0.25f * (L.z + 2.f * C.z + Rt.z);
        h.w = 0.25f * (L.w + 2.f * C.w + Rt.w);
    } else {
        // border: scalar with replicate clamp
        float hv[4];
#pragma unroll
        for (int j = 0; j < 4; ++j) {
            int xc = x0 + j;
            int xl = xc - R; if (xl < 0) xl = 0;
            int xr = xc + R; if (xr > IMG_W - 1) xr = IMG_W - 1;
            hv[j] = 0.25f * (load1<DIFF>(a, b, xl)
                   + 2.f  *  load1<DIFF>(a, b, xc)
                   +         load1<DIFF>(a, b, xr));
        }
        h = make_float4(hv[0], hv[1], hv[2], hv[3]);
    }
    return h;
}

// MODE 0: dst = Br(src)
// MODE 1: dst = Br(src - src2)            (src=hq, src2=lq)
// MODE 2: dst = clip(src2 - Br(src), +-1) (src=prev level, src2=hq)
template<int R, int MODE>
__global__ __launch_bounds__(256) void wavelet_blur_kernel(
        const float* __restrict__ src, const float* __restrict__ src2,
        float* __restrict__ dst) {
    const int x0 = (blockIdx.x * 64 + threadIdx.x) * 4;
    const int y  = blockIdx.y * 4 + threadIdx.y;
    const int p  = blockIdx.z;
    const size_t base = (size_t)p * (size_t)(IMG_H * IMG_W);

    constexpr bool DIFF = (MODE == 1);
    const float* A = src + base;
    const float* B = DIFF ? (src2 + base) : A;   // B unused unless DIFF

    const int ym = (y - R < 0) ? 0 : (y - R);
    const int yp = (y + R > IMG_H - 1) ? (IMG_H - 1) : (y + R);

    float4 h0 = hblur<R, DIFF>(A + (size_t)ym * IMG_W, B + (size_t)ym * IMG_W, x0);
    float4 h1 = hblur<R, DIFF>(A + (size_t)y  * IMG_W, B + (size_t)y  * IMG_W, x0);
    float4 h2 = hblur<R, DIFF>(A + (size_t)yp * IMG_W, B + (size_t)yp * IMG_W, x0);

    float4 v;
    v.x = 0.25f * (h0.x + 2.f * h1.x + h2.x);
    v.y = 0.25f * (h0.y + 2.f * h1.y + h2.y);
    v.z = 0.25f * (h0.z + 2.f * h1.z + h2.z);
    v.w = 0.25f * (h0.w + 2.f * h1.w + h2.w);

    if constexpr (MODE == 2) {
        float4 hc = ld4(src2 + base + (size_t)y * IMG_W + x0);
        v.x = fminf(fmaxf(hc.x - v.x, -1.f), 1.f);
        v.y = fminf(fmaxf(hc.y - v.y, -1.f), 1.f);
        v.z = fminf(fmaxf(hc.z - v.z, -1.f), 1.f);
        v.w = fminf(fmaxf(hc.w - v.w, -1.f), 1.f);
    }
    st4(dst + base + (size_t)y * IMG_W + x0, v);
}

extern "C" void kernel_launch(void* const* d_in, const int* in_sizes, int n_in,
                              void* d_out, int out_size, void* d_ws, size_t ws_size,
                              hipStream_t stream) {
    const float* hq = (const float*)d_in[0];
    const float* lq = (const float*)d_in[1];
    float* out = (float*)d_out;
    float* ws  = (float*)d_ws;

    // 1280 px / (64 threads * 4 px) = 5 blocks in x; 720/4 rows; 48 planes
    dim3 block(64, 4, 1);
    dim3 grid(5, 180, 48);

    // ping-pong: d_out and d_ws as the two intermediate buffers
    wavelet_blur_kernel<1,  1><<<grid, block, 0, stream>>>(hq,  lq, out); // w1 = B1(hq-lq)
    wavelet_blur_kernel<2,  0><<<grid, block, 0, stream>>>(out, nullptr, ws);  // w2 = B2(w1)
    wavelet_blur_kernel<4,  0><<<grid, block, 0, stream>>>(ws,  nullptr, out); // w3 = B4(w2)
    wavelet_blur_kernel<8,  0><<<grid, block, 0, stream>>>(out, nullptr, ws);  // w4 = B8(w3)
    wavelet_blur_kernel<16, 2><<<grid, block, 0, stream>>>(ws,  hq, out);      // out = clip(hq - B16(w4))
}

// Round 2
// 692.242 us; speedup vs baseline: 1.3864x; 1.3864x over previous
//
#include <hip/hip_runtime.h>
#include <hip/hip_fp16.h>

// out = clip(hq - L(hq - lq), -1, 1),  L = B16.B8.B4.B2.B1 (dilated 3x3 binomial, replicate pad)
// Fully fused: one kernel, 5 levels computed on an LDS-resident fp16 tile.
// Tile: 120x128 output, halo 32 -> region 184 rows x 192 cols (stride 200 halves).
// In-place passes with register staging; tap coords clamp to image bounds at every level.

static constexpr int IMG_H = 720;
static constexpr int IMG_W = 1280;
static constexpr int TH = 120, TW = 128;
static constexpr int TX_N = 10, TY_N = 6, NPL = 48;
static constexpr int STRIDE = 200;                 // halves per LDS row (192 used + pad)
static constexpr int BUF_HALVES = 185 * STRIDE;    // 184 rows + 1 pad row = 74,000 B

__device__ __forceinline__ float4 ld4(const float* p) {
    return *reinterpret_cast<const float4*>(p);
}
__device__ __forceinline__ void st4(float* p, const float4& v) {
    *reinterpret_cast<float4*>(p) = v;
}

__device__ __forceinline__ void load8f(const __half* src, float* f) {
    union { int4 i4; __half2 h2[4]; } u;
    u.i4 = *reinterpret_cast<const int4*>(src);
#pragma unroll
    for (int i = 0; i < 4; ++i) {
        f[2 * i]     = __low2float(u.h2[i]);
        f[2 * i + 1] = __high2float(u.h2[i]);
    }
}
__device__ __forceinline__ int4 pack8h(const float* v) {
    union { __half2 h2[4]; int4 i4; } u;
#pragma unroll
    for (int i = 0; i < 4; ++i)
        u.h2[i] = __floats2half2_rn(v[2 * i], v[2 * i + 1]);
    return u.i4;
}

// One blur pass, in place on buf, with register staging.
// Region rows [RLO,RHI]; col chunks lc0 = B0 + 8*c, c in [0,NC). Taps clamp to
// image bounds given via XLO/XHI (cols, lc-space) and YLO/YHI (rows, lr-space);
// sentinels (+-100000) for non-edge blocks.
template<int R, int RLO, int RHI, int B0, int NC, bool VERT>
__device__ void pass(__half* buf, int tid, int XLO, int XHI, int YLO, int YHI, bool edgex) {
    constexpr int NR = RHI - RLO + 1;
    constexpr int NCH = NR * NC;
    constexpr int ITERS = (NCH + 511) / 512;
    int4 stage[ITERS];
#pragma unroll
    for (int k = 0; k < ITERS; ++k) {
        int idx = tid + k * 512;
        if (idx < NCH) {
            int lr  = RLO + idx / NC;
            int lc0 = B0 + (idx % NC) * 8;
            float o[8];
            if constexpr (VERT) {
                int lrm = lr - R; if (lrm < YLO) lrm = YLO;
                int lrp = lr + R; if (lrp > YHI) lrp = YHI;
                float a[8], b[8], c[8];
                load8f(buf + lrm * STRIDE + lc0, a);
                load8f(buf + lr  * STRIDE + lc0, b);
                load8f(buf + lrp * STRIDE + lc0, c);
#pragma unroll
                for (int j = 0; j < 8; ++j)
                    o[j] = 0.25f * (a[j] + 2.f * b[j] + c[j]);
            } else {
                bool clampx = edgex && (lc0 - R < XLO || lc0 + 7 + R > XHI);
                if (!clampx) {
                    if constexpr (R <= 8) {
                        float f[24];
                        load8f(buf + lr * STRIDE + lc0 - 8, f);
                        load8f(buf + lr * STRIDE + lc0,     f + 8);
                        load8f(buf + lr * STRIDE + lc0 + 8, f + 16);
#pragma unroll
                        for (int j = 0; j < 8; ++j)
                            o[j] = 0.25f * (f[8 + j - R] + 2.f * f[8 + j] + f[8 + j + R]);
                    } else {
                        float a[8], b[8], c[8];
                        load8f(buf + lr * STRIDE + lc0 - 16, a);
                        load8f(buf + lr * STRIDE + lc0,      b);
                        load8f(buf + lr * STRIDE + lc0 + 16, c);
#pragma unroll
                        for (int j = 0; j < 8; ++j)
                            o[j] = 0.25f * (a[j] + 2.f * b[j] + c[j]);
                    }
                } else {
                    // per-element x-clamped (only tx-edge blocks, few chunks)
#pragma unroll
                    for (int j = 0; j < 8; ++j) {
                        int lc = lc0 + j;
                        int ml = lc - R; if (ml < XLO) ml = XLO;
                        int mr = lc + R; if (mr > XHI) mr = XHI;
                        float a = __half2float(buf[lr * STRIDE + ml]);
                        float b = __half2float(buf[lr * STRIDE + lc]);
                        float c = __half2float(buf[lr * STRIDE + mr]);
                        o[j] = 0.25f * (a + 2.f * b + c);
                    }
                }
            }
            stage[k] = pack8h(o);
        }
    }
    __syncthreads();
#pragma unroll
    for (int k = 0; k < ITERS; ++k) {
        int idx = tid + k * 512;
        if (idx < NCH) {
            int lr  = RLO + idx / NC;
            int lc0 = B0 + (idx % NC) * 8;
            *reinterpret_cast<int4*>(buf + lr * STRIDE + lc0) = stage[k];
        }
    }
    __syncthreads();
}

__global__ __launch_bounds__(512, 4) void wavelet_fused_kernel(
        const float* __restrict__ hq, const float* __restrict__ lq,
        float* __restrict__ out) {
    __shared__ __align__(16) __half buf[BUF_HALVES];

    // XCD-aware swizzle (2880 % 8 == 0 -> simple bijective form)
    const int nwg = NPL * TY_N * TX_N;      // 2880
    const int cpx = nwg / 8;                // 360
    int bid = blockIdx.x;
    int swz = (bid % 8) * cpx + bid / 8;
    const int tx = swz % TX_N;
    const int ty = (swz / TX_N) % TY_N;
    const int p  = swz / (TX_N * TY_N);

    const int tid = threadIdx.x;
    const size_t plane = (size_t)p * (size_t)(IMG_H * IMG_W);
    const float* hp = hq + plane;
    const float* lp = lq + plane;
    float* op = out + plane;

    const int Y0 = ty * TH, X0 = tx * TW;
    const int RY0 = Y0 - 32, RX0 = X0 - 32;
    const bool edgex = (tx == 0) || (tx == TX_N - 1);
    const int XLO = (tx == 0)        ?  32 : -100000;   // lc of image x=0
    const int XHI = (tx == TX_N - 1) ? 159 :  100000;   // lc of image x=1279
    const int YLO = (ty == 0)        ?  32 : -100000;   // lr of image y=0
    const int YHI = (ty == TY_N - 1) ? 151 :  100000;   // lr of image y=719

    // ---- load phase: d = hq - lq into fp16 region (184 rows x 24 chunks) ----
#pragma unroll
    for (int k = 0; k < 9; ++k) {
        int idx = tid + k * 512;
        if (idx < 184 * 24) {
            int lr  = idx / 24;
            int lc0 = (idx % 24) * 8;
            int gy = RY0 + lr; gy = gy < 0 ? 0 : (gy > IMG_H - 1 ? IMG_H - 1 : gy);
            int gx0 = RX0 + lc0;
            const float* hrow = hp + (size_t)gy * IMG_W;
            const float* lrow = lp + (size_t)gy * IMG_W;
            float v[8];
            if (gx0 >= 0 && gx0 + 7 <= IMG_W - 1) {
                float4 a0 = ld4(hrow + gx0), a1 = ld4(hrow + gx0 + 4);
                float4 b0 = ld4(lrow + gx0), b1 = ld4(lrow + gx0 + 4);
                v[0] = a0.x - b0.x; v[1] = a0.y - b0.y; v[2] = a0.z - b0.z; v[3] = a0.w - b0.w;
                v[4] = a1.x - b1.x; v[5] = a1.y - b1.y; v[6] = a1.z - b1.z; v[7] = a1.w - b1.w;
            } else {
#pragma unroll
                for (int j = 0; j < 8; ++j) {
                    int gx = gx0 + j; gx = gx < 0 ? 0 : (gx > IMG_W - 1 ? IMG_W - 1 : gx);
                    v[j] = hrow[gx] - lrow[gx];
                }
            }
            *reinterpret_cast<int4*>(buf + lr * STRIDE + lc0) = pack8h(v);
        }
    }
    __syncthreads();

    // ---- 9 in-place passes (H1..H5, V1..V4) ----
    pass< 1,  1, 182,  0, 24, false>(buf, tid, XLO, XHI, YLO, YHI, edgex);  // H1
    pass< 1,  2, 181,  0, 24, true >(buf, tid, XLO, XHI, YLO, YHI, edgex);  // V1
    pass< 2,  2, 181,  0, 24, false>(buf, tid, XLO, XHI, YLO, YHI, edgex);  // H2
    pass< 2,  4, 179,  0, 24, true >(buf, tid, XLO, XHI, YLO, YHI, edgex);  // V2
    pass< 4,  4, 179,  8, 22, false>(buf, tid, XLO, XHI, YLO, YHI, edgex);  // H3
    pass< 4,  8, 175,  8, 22, true >(buf, tid, XLO, XHI, YLO, YHI, edgex);  // V3
    pass< 8,  8, 175, 16, 20, false>(buf, tid, XLO, XHI, YLO, YHI, edgex);  // H4
    pass< 8, 16, 167, 16, 20, true >(buf, tid, XLO, XHI, YLO, YHI, edgex);  // V4
    pass<16, 16, 167, 32, 16, false>(buf, tid, XLO, XHI, YLO, YHI, edgex);  // H5

    // ---- V5 fused with clip + store (rows lr 32..151, cols lc0 = 32+8c, c<16) ----
#pragma unroll
    for (int k = 0; k < 4; ++k) {
        int idx = tid + k * 512;
        if (idx < 120 * 16) {
            int r = idx / 16, c = idx % 16;
            int lr = 32 + r, lc0 = 32 + c * 8;
            int lrm = lr - 16; if (lrm < YLO) lrm = YLO;
            int lrp = lr + 16; if (lrp > YHI) lrp = YHI;
            float a[8], b[8], cc[8];
            load8f(buf + lrm * STRIDE + lc0, a);
            load8f(buf + lr  * STRIDE + lc0, b);
            load8f(buf + lrp * STRIDE + lc0, cc);
            int gy = Y0 + r, gx0 = X0 + c * 8;
            const float* hrow = hp + (size_t)gy * IMG_W + gx0;
            float4 q0 = ld4(hrow), q1 = ld4(hrow + 4);
            float q[8] = {q0.x, q0.y, q0.z, q0.w, q1.x, q1.y, q1.z, q1.w};
            float o[8];
#pragma unroll
            for (int j = 0; j < 8; ++j) {
                float v = 0.25f * (a[j] + 2.f * b[j] + cc[j]);
                o[j] = fminf(fmaxf(q[j] - v, -1.f), 1.f);
            }
            float* orow = op + (size_t)gy * IMG_W + gx0;
            st4(orow,     make_float4(o[0], o[1], o[2], o[3]));
            st4(orow + 4, make_float4(o[4], o[5], o[6], o[7]));
        }
    }
}

extern "C" void kernel_launch(void* const* d_in, const int* in_sizes, int n_in,
                              void* d_out, int out_size, void* d_ws, size_t ws_size,
                              hipStream_t stream) {
    const float* hq = (const float*)d_in[0];
    const float* lq = (const float*)d_in[1];
    float* out = (float*)d_out;

    wavelet_fused_kernel<<<dim3(NPL * TY_N * TX_N), dim3(512), 0, stream>>>(hq, lq, out);
}

// Round 3
// 575.510 us; speedup vs baseline: 1.6676x; 1.2028x over previous
//
#include <hip/hip_runtime.h>
#include <hip/hip_fp16.h>

// out = clip(hq - L(hq - lq), -1, 1),  L = B16.B8.B4.B2.B1 (dilated 3x3 binomial, replicate pad)
// Fully fused: one kernel, 5 levels on an LDS-resident fp16 tile (fp32 arithmetic).
// Tile: 120x128 output, halo 32 -> region 184x192 (stride 200 halves).
// In-place passes, register-staged, SPLIT INTO PHASES along the hazard-free axis
// (rows for H passes, cols for V passes) so staging stays <= 4 int4 = 16 VGPRs (no spills).

static constexpr int IMG_H = 720;
static constexpr int IMG_W = 1280;
static constexpr int TH = 120, TW = 128;
static constexpr int TX_N = 10, TY_N = 6, NPL = 48;
static constexpr int STRIDE = 200;                 // halves per LDS row
static constexpr int BUF_HALVES = 185 * STRIDE;    // 74,000 B -> 2 blocks/CU

__device__ __forceinline__ float4 ld4(const float* p) {
    return *reinterpret_cast<const float4*>(p);
}
__device__ __forceinline__ void st4(float* p, const float4& v) {
    *reinterpret_cast<float4*>(p) = v;
}

__device__ __forceinline__ void load8f(const __half* src, float* f) {
    union { int4 i4; __half2 h2[4]; } u;
    u.i4 = *reinterpret_cast<const int4*>(src);
#pragma unroll
    for (int i = 0; i < 4; ++i) {
        f[2 * i]     = __low2float(u.h2[i]);
        f[2 * i + 1] = __high2float(u.h2[i]);
    }
}
__device__ __forceinline__ int4 pack8h(const float* v) {
    union { __half2 h2[4]; int4 i4; } u;
#pragma unroll
    for (int i = 0; i < 4; ++i)
        u.h2[i] = __floats2half2_rn(v[2 * i], v[2 * i + 1]);
    return u.i4;
}

// One in-place blur pass, split into NPH phases.
// H pass (VERT=false): phases partition ROWS (rows are independent).
// V pass (VERT=true):  phases partition COL-CHUNKS (cols are independent).
// Taps clamp to image bounds (XLO/XHI in lc-space, YLO/YHI in lr-space; sentinels otherwise).
template<int R, int RLO, int RHI, int B0, int NC, bool VERT, int NPH>
__device__ void pass(__half* buf, int tid, int XLO, int XHI, int YLO, int YHI, bool edgex) {
    constexpr int NR = RHI - RLO + 1;
    if constexpr (!VERT) {
        constexpr int RPP   = (NR + NPH - 1) / NPH;      // rows per phase
        constexpr int ITERS = (RPP * NC + 511) / 512;
#pragma unroll
        for (int ph = 0; ph < NPH; ++ph) {
            const int r0   = RLO + ph * RPP;
            const int nrow = (NR - ph * RPP) < RPP ? (NR - ph * RPP) : RPP;
            const int nch  = nrow * NC;
            int4 stage[ITERS];
#pragma unroll
            for (int k = 0; k < ITERS; ++k) {
                int idx = tid + k * 512;
                if (idx < nch) {
                    int lr  = r0 + idx / NC;
                    int lc0 = B0 + (idx % NC) * 8;
                    float o[8];
                    bool clampx = edgex && (lc0 - R < XLO || lc0 + 7 + R > XHI);
                    if (!clampx) {
                        if constexpr (R <= 8) {
                            float f[24];
                            load8f(buf + lr * STRIDE + lc0 - 8, f);
                            load8f(buf + lr * STRIDE + lc0,     f + 8);
                            load8f(buf + lr * STRIDE + lc0 + 8, f + 16);
#pragma unroll
                            for (int j = 0; j < 8; ++j)
                                o[j] = 0.25f * (f[8 + j - R] + 2.f * f[8 + j] + f[8 + j + R]);
                        } else {
                            float a[8], b[8], c[8];
                            load8f(buf + lr * STRIDE + lc0 - 16, a);
                            load8f(buf + lr * STRIDE + lc0,      b);
                            load8f(buf + lr * STRIDE + lc0 + 16, c);
#pragma unroll
                            for (int j = 0; j < 8; ++j)
                                o[j] = 0.25f * (a[j] + 2.f * b[j] + c[j]);
                        }
                    } else {
#pragma unroll
                        for (int j = 0; j < 8; ++j) {
                            int lc = lc0 + j;
                            int ml = lc - R; if (ml < XLO) ml = XLO;
                            int mr = lc + R; if (mr > XHI) mr = XHI;
                            float a = __half2float(buf[lr * STRIDE + ml]);
                            float b = __half2float(buf[lr * STRIDE + lc]);
                            float c = __half2float(buf[lr * STRIDE + mr]);
                            o[j] = 0.25f * (a + 2.f * b + c);
                        }
                    }
                    stage[k] = pack8h(o);
                }
            }
            __syncthreads();
#pragma unroll
            for (int k = 0; k < ITERS; ++k) {
                int idx = tid + k * 512;
                if (idx < nch) {
                    int lr  = r0 + idx / NC;
                    int lc0 = B0 + (idx % NC) * 8;
                    *reinterpret_cast<int4*>(buf + lr * STRIDE + lc0) = stage[k];
                }
            }
            __syncthreads();
        }
    } else {
        constexpr int CPP   = NC / NPH;                  // col-chunks per phase (exact)
        constexpr int NCH   = NR * CPP;
        constexpr int ITERS = (NCH + 511) / 512;
#pragma unroll
        for (int ph = 0; ph < NPH; ++ph) {
            const int c0 = B0 + ph * CPP * 8;
            int4 stage[ITERS];
#pragma unroll
            for (int k = 0; k < ITERS; ++k) {
                int idx = tid + k * 512;
                if (idx < NCH) {
                    int lr  = RLO + idx / CPP;
                    int lc0 = c0 + (idx % CPP) * 8;
                    int lrm = lr - R; if (lrm < YLO) lrm = YLO;
                    int lrp = lr + R; if (lrp > YHI) lrp = YHI;
                    float a[8], b[8], c[8];
                    load8f(buf + lrm * STRIDE + lc0, a);
                    load8f(buf + lr  * STRIDE + lc0, b);
                    load8f(buf + lrp * STRIDE + lc0, c);
                    float o[8];
#pragma unroll
                    for (int j = 0; j < 8; ++j)
                        o[j] = 0.25f * (a[j] + 2.f * b[j] + c[j]);
                    stage[k] = pack8h(o);
                }
            }
            __syncthreads();
#pragma unroll
            for (int k = 0; k < ITERS; ++k) {
                int idx = tid + k * 512;
                if (idx < NCH) {
                    int lr  = RLO + idx / CPP;
                    int lc0 = c0 + (idx % CPP) * 8;
                    *reinterpret_cast<int4*>(buf + lr * STRIDE + lc0) = stage[k];
                }
            }
            __syncthreads();
        }
    }
}

__global__ __launch_bounds__(512)
__attribute__((amdgpu_waves_per_eu(4, 4)))   // LDS caps us at 2 blocks/CU anyway; allow up to 128 VGPR
void wavelet_fused_kernel(
        const float* __restrict__ hq, const float* __restrict__ lq,
        float* __restrict__ out) {
    __shared__ __align__(16) __half buf[BUF_HALVES];

    // XCD-aware swizzle (2880 % 8 == 0 -> simple bijective form)
    const int nwg = NPL * TY_N * TX_N;      // 2880
    const int cpx = nwg / 8;                // 360
    int bid = blockIdx.x;
    int swz = (bid % 8) * cpx + bid / 8;
    const int tx = swz % TX_N;
    const int ty = (swz / TX_N) % TY_N;
    const int p  = swz / (TX_N * TY_N);

    const int tid = threadIdx.x;
    const size_t plane = (size_t)p * (size_t)(IMG_H * IMG_W);
    const float* hp = hq + plane;
    const float* lp = lq + plane;
    float* op = out + plane;

    const int Y0 = ty * TH, X0 = tx * TW;
    const int RY0 = Y0 - 32, RX0 = X0 - 32;
    const bool edgex = (tx == 0) || (tx == TX_N - 1);
    const int XLO = (tx == 0)        ?  32 : -100000;   // lc of image x=0
    const int XHI = (tx == TX_N - 1) ? 159 :  100000;   // lc of image x=1279
    const int YLO = (ty == 0)        ?  32 : -100000;   // lr of image y=0
    const int YHI = (ty == TY_N - 1) ? 151 :  100000;   // lr of image y=719

    // ---- load phase: d = hq - lq into fp16 region (184 rows x 24 chunks) ----
#pragma unroll
    for (int k = 0; k < 9; ++k) {
        int idx = tid + k * 512;
        if (idx < 184 * 24) {
            int lr  = idx / 24;
            int lc0 = (idx % 24) * 8;
            int gy = RY0 + lr; gy = gy < 0 ? 0 : (gy > IMG_H - 1 ? IMG_H - 1 : gy);
            int gx0 = RX0 + lc0;
            const float* hrow = hp + (size_t)gy * IMG_W;
            const float* lrow = lp + (size_t)gy * IMG_W;
            float v[8];
            if (gx0 >= 0 && gx0 + 7 <= IMG_W - 1) {
                float4 a0 = ld4(hrow + gx0), a1 = ld4(hrow + gx0 + 4);
                float4 b0 = ld4(lrow + gx0), b1 = ld4(lrow + gx0 + 4);
                v[0] = a0.x - b0.x; v[1] = a0.y - b0.y; v[2] = a0.z - b0.z; v[3] = a0.w - b0.w;
                v[4] = a1.x - b1.x; v[5] = a1.y - b1.y; v[6] = a1.z - b1.z; v[7] = a1.w - b1.w;
            } else {
#pragma unroll
                for (int j = 0; j < 8; ++j) {
                    int gx = gx0 + j; gx = gx < 0 ? 0 : (gx > IMG_W - 1 ? IMG_W - 1 : gx);
                    v[j] = hrow[gx] - lrow[gx];
                }
            }
            *reinterpret_cast<int4*>(buf + lr * STRIDE + lc0) = pack8h(v);
        }
    }
    __syncthreads();

    // ---- 9 in-place passes (phase counts keep staging <= 4 int4) ----
    pass< 1,  1, 182,  0, 24, false, 3>(buf, tid, XLO, XHI, YLO, YHI, edgex);  // H1
    pass< 1,  2, 181,  0, 24, true , 3>(buf, tid, XLO, XHI, YLO, YHI, edgex);  // V1
    pass< 2,  2, 181,  0, 24, false, 3>(buf, tid, XLO, XHI, YLO, YHI, edgex);  // H2
    pass< 2,  4, 179,  0, 24, true , 3>(buf, tid, XLO, XHI, YLO, YHI, edgex);  // V2
    pass< 4,  4, 179,  8, 22, false, 2>(buf, tid, XLO, XHI, YLO, YHI, edgex);  // H3
    pass< 4,  8, 175,  8, 22, true , 2>(buf, tid, XLO, XHI, YLO, YHI, edgex);  // V3
    pass< 8,  8, 175, 16, 20, false, 2>(buf, tid, XLO, XHI, YLO, YHI, edgex);  // H4
    pass< 8, 16, 167, 16, 20, true , 2>(buf, tid, XLO, XHI, YLO, YHI, edgex);  // V4
    pass<16, 16, 167, 32, 16, false, 2>(buf, tid, XLO, XHI, YLO, YHI, edgex);  // H5

    // ---- V5 fused with clip + store (rows lr 32..151, cols lc0 = 32+8c, c<16) ----
#pragma unroll
    for (int k = 0; k < 4; ++k) {
        int idx = tid + k * 512;
        if (idx < 120 * 16) {
            int r = idx / 16, c = idx % 16;
            int lr = 32 + r, lc0 = 32 + c * 8;
            int lrm = lr - 16; if (lrm < YLO) lrm = YLO;
            int lrp = lr + 16; if (lrp > YHI) lrp = YHI;
            float a[8], b[8], cc[8];
            load8f(buf + lrm * STRIDE + lc0, a);
            load8f(buf + lr  * STRIDE + lc0, b);
            load8f(buf + lrp * STRIDE + lc0, cc);
            int gy = Y0 + r, gx0 = X0 + c * 8;
            const float* hrow = hp + (size_t)gy * IMG_W + gx0;
            float4 q0 = ld4(hrow), q1 = ld4(hrow + 4);
            float q[8] = {q0.x, q0.y, q0.z, q0.w, q1.x, q1.y, q1.z, q1.w};
            float o[8];
#pragma unroll
            for (int j = 0; j < 8; ++j) {
                float v = 0.25f * (a[j] + 2.f * b[j] + cc[j]);
                o[j] = fminf(fmaxf(q[j] - v, -1.f), 1.f);
            }
            float* orow = op + (size_t)gy * IMG_W + gx0;
            st4(orow,     make_float4(o[0], o[1], o[2], o[3]));
            st4(orow + 4, make_float4(o[4], o[5], o[6], o[7]));
        }
    }
}

extern "C" void kernel_launch(void* const* d_in, const int* in_sizes, int n_in,
                              void* d_out, int out_size, void* d_ws, size_t ws_size,
                              hipStream_t stream) {
    const float* hq = (const float*)d_in[0];
    const float* lq = (const float*)d_in[1];
    float* out = (float*)d_out;

    wavelet_fused_kernel<<<dim3(NPL * TY_N * TX_N), dim3(512), 0, stream>>>(hq, lq, out);
}